// Round 12
// baseline (263.984 us; speedup 1.0000x reference)
//
#include <hip/hip_runtime.h>
#include <hip/hip_bf16.h>

// Shapes (fixed by the problem)
#define BATCH  4
#define TSEQ   2048
#define CDIM   1024
#define NHEAD  16
#define DHEAD  64
#define MROWS  (BATCH * TSEQ)      // 8192
#define QKVCOL (3 * CDIM)          // 3072

typedef __bf16 bf16x8 __attribute__((ext_vector_type(8)));
typedef float  f32x4  __attribute__((ext_vector_type(4)));

// hardware exp2 (v_exp_f32). __exp2f collides with a glibc macro (R12).
#define EXP2F(x) __builtin_amdgcn_exp2f(x)

__device__ __forceinline__ unsigned short f2bf(float f) {
  union { float f; unsigned int i; } v; v.f = f;
  unsigned int i = v.i;
  return (unsigned short)((i + 0x7fffu + ((i >> 16) & 1u)) >> 16);  // RNE
}

__device__ __forceinline__ void load16_to_lds(const void* g, void* l) {
  __builtin_amdgcn_global_load_lds(
      (const __attribute__((address_space(1))) unsigned int*)g,
      (__attribute__((address_space(3))) unsigned int*)l, 16, 0, 0);
}

// ---------------------------------------------------------------------------
// prep_all (VERIFIED R11): cast x->bf16 + transpose_cast(w_qkv) +
// transpose_cast(w_out) merged into ONE launch. UNCHANGED.
// ---------------------------------------------------------------------------
__global__ __launch_bounds__(256) void prep_all(
    const float* __restrict__ x,     unsigned short* __restrict__ xb,
    const float* __restrict__ w_qkv, unsigned short* __restrict__ wqkvT,
    const float* __restrict__ w_out, unsigned short* __restrict__ woutT) {
  __shared__ float tile[64][68];
  const int id = blockIdx.x;
  const int t  = threadIdx.x;

  if (id < 4096) {
    // ---- cast x -> bf16 (8 elems/thread) ----
    const int i = (id * 256 + t) * 8;
    float4 a = *(const float4*)(x + i);
    float4 b = *(const float4*)(x + i + 4);
    unsigned short v[8] = {f2bf(a.x), f2bf(a.y), f2bf(a.z), f2bf(a.w),
                           f2bf(b.x), f2bf(b.y), f2bf(b.z), f2bf(b.w)};
    *(uint4*)(xb + i) = *(const uint4*)v;
    return;
  }

  // ---- transpose+cast a weight matrix: fp32 [R=1024, C] -> bf16 [C, 1024] ----
  const float* in;
  unsigned short* out;
  int C, bx, by;
  if (id < 4096 + 768) {
    const int t1 = id - 4096;
    in = w_qkv; out = wqkvT; C = QKVCOL;
    bx = t1 % 48; by = t1 / 48;
  } else {
    const int t2 = id - 4096 - 768;
    in = w_out; out = woutT; C = CDIM;
    bx = t2 & 15; by = t2 >> 4;
  }
  const int R  = CDIM;
  const int r0 = by * 64;
  const int c0 = bx * 64;
  const int tr = t >> 2;
  const int tc = (t & 3) * 16;

  const float4* src = (const float4*)(in + (size_t)(r0 + tr) * C + c0 + tc);
#pragma unroll
  for (int i = 0; i < 4; i++)
    *(float4*)&tile[tr][tc + 4 * i] = src[i];
  __syncthreads();

  unsigned short vals[16];
#pragma unroll
  for (int k = 0; k < 16; k++) vals[k] = f2bf(tile[tc + k][tr]);
  uint4* dst = (uint4*)(out + (size_t)(c0 + tr) * R + r0 + tc);
  dst[0] = ((const uint4*)vals)[0];
  dst[1] = ((const uint4*)vals)[1];
}

// ---------------------------------------------------------------------------
// QKV GEMM, BK=64 swizzled staging — VERIFIED R9/R11 (~77µs, absmax
// 0.015625, 0 conflicts). V^T fused epilogue + Q scale 0.125*log2(e).
// UNCHANGED.
// ---------------------------------------------------------------------------
__global__ __launch_bounds__(256) void gemm_qkv(
    const unsigned short* __restrict__ A, const unsigned short* __restrict__ Bt,
    unsigned short* __restrict__ Qb, unsigned short* __restrict__ Kb,
    unsigned short* __restrict__ vt) {
  __shared__ unsigned short ldsA[128 * 64];
  __shared__ unsigned short ldsB[128 * 64];

  const int tid  = threadIdx.x;
  const int lane = tid & 63;
  const int wave = tid >> 6;
  const int m0   = blockIdx.y * 128;
  const int n0   = blockIdx.x * 128;
  const int wr   = wave >> 1;
  const int wc   = wave & 1;
  const int quad = lane >> 4;
  const int l16  = lane & 15;

  f32x4 acc[4][4] = {};
  const int rsub = lane >> 3;          // 0..7   (row within 8-row chunk)
  const int csub = (lane & 7) * 8;     // 0..56  (col granule)

  // hoisted conflict-free read bases (v7 formulas, 64-elem rows)
  const int cx34 = (quad * 8) ^ ((l16 & 3) << 3);
  const int rb0  = l16 * 64 + ((l16 & 4) << 3) + cx34;          // ks=0
  const int rb1  = l16 * 64 + (32 ^ ((l16 & 4) << 3)) + cx34;   // ks=1

  for (int k0 = 0; k0 < CDIM; k0 += 64) {
    __syncthreads();
#pragma unroll
    for (int i = 0; i < 4; i++) {
      const int rowbase = i * 32 + wave * 8;
      const int row  = rowbase + rsub;
      const int colS = csub ^ ((row & 7) * 8);   // pre-swizzled source
      load16_to_lds(A  + (size_t)(m0 + row) * CDIM + k0 + colS, &ldsA[rowbase * 64]);
      load16_to_lds(Bt + (size_t)(n0 + row) * CDIM + k0 + colS, &ldsB[rowbase * 64]);
    }
    __syncthreads();

    bf16x8 fa[4][2], fb[4][2];
#pragma unroll
    for (int i = 0; i < 4; i++) {
      fa[i][0] = *(const bf16x8*)&ldsA[wr * 4096 + i * 1024 + rb0];
      fa[i][1] = *(const bf16x8*)&ldsA[wr * 4096 + i * 1024 + rb1];
    }
#pragma unroll
    for (int j = 0; j < 4; j++) {
      fb[j][0] = *(const bf16x8*)&ldsB[wc * 4096 + j * 1024 + rb0];
      fb[j][1] = *(const bf16x8*)&ldsB[wc * 4096 + j * 1024 + rb1];
    }

#pragma unroll
    for (int i = 0; i < 4; i++)
#pragma unroll
      for (int j = 0; j < 4; j++) {
        acc[i][j] = __builtin_amdgcn_mfma_f32_16x16x32_bf16(fa[i][0], fb[j][0], acc[i][j], 0, 0, 0);
        acc[i][j] = __builtin_amdgcn_mfma_f32_16x16x32_bf16(fa[i][1], fb[j][1], acc[i][j], 0, 0, 0);
      }
  }

  const int seg = n0 >> 10;                       // 0=Q 1=K 2=V
  if (seg == 2) {
    // V: write directly transposed into vt [b*16+h][d][t] (bit-exact values)
#pragma unroll
    for (int i = 0; i < 4; i++) {
      const int row = m0 + wr * 64 + i * 16 + quad * 4;   // = b*2048 + t0
      const int bb  = row >> 11;
      const int t0  = row & 2047;                          // t0 % 4 == 0
#pragma unroll
      for (int j = 0; j < 4; j++) {
        const int col = ((n0 & 1023) + wc * 64 + j * 16 + l16);  // h*64+d
        unsigned short v4[4];
#pragma unroll
        for (int r = 0; r < 4; r++) v4[r] = f2bf(acc[i][j][r]);
        *(uint2*)(vt + ((size_t)(bb * 16 + (col >> 6)) * 64 + (col & 63)) * TSEQ + t0)
            = *(const uint2*)v4;
      }
    }
  } else {
    unsigned short* dst = seg == 0 ? Qb : Kb;
    const float scl = seg == 0 ? 0.18033688f : 1.0f;  // 0.125*log2(e)
#pragma unroll
    for (int i = 0; i < 4; i++) {
      const int row = m0 + wr * 64 + i * 16 + quad * 4;
#pragma unroll
      for (int j = 0; j < 4; j++) {
        const int col = ((n0 & 1023) + wc * 64 + j * 16 + l16);
#pragma unroll
        for (int r = 0; r < 4; r++)
          dst[(size_t)(row + r) * CDIM + col] = f2bf(acc[i][j][r] * scl);
      }
    }
  }
}

// ---------------------------------------------------------------------------
// Out-projection GEMM, BK=64 swizzled staging — VERIFIED R9/R11. UNCHANGED.
// ---------------------------------------------------------------------------
__global__ __launch_bounds__(256) void gemm_out(
    const unsigned short* __restrict__ A, const unsigned short* __restrict__ Bt,
    float* __restrict__ Cmat, const float* __restrict__ bias) {
  __shared__ unsigned short ldsA[128 * 64];
  __shared__ unsigned short ldsB[128 * 64];

  const int tid  = threadIdx.x;
  const int lane = tid & 63;
  const int wave = tid >> 6;
  const int m0   = blockIdx.y * 128;
  const int n0   = blockIdx.x * 128;
  const int wr   = wave >> 1;
  const int wc   = wave & 1;
  const int quad = lane >> 4;
  const int l16  = lane & 15;

  f32x4 acc[4][4] = {};
  const int rsub = lane >> 3;
  const int csub = (lane & 7) * 8;

  const int cx34 = (quad * 8) ^ ((l16 & 3) << 3);
  const int rb0  = l16 * 64 + ((l16 & 4) << 3) + cx34;
  const int rb1  = l16 * 64 + (32 ^ ((l16 & 4) << 3)) + cx34;

  for (int k0 = 0; k0 < CDIM; k0 += 64) {
    __syncthreads();
#pragma unroll
    for (int i = 0; i < 4; i++) {
      const int rowbase = i * 32 + wave * 8;
      const int row  = rowbase + rsub;
      const int colS = csub ^ ((row & 7) * 8);
      load16_to_lds(A  + (size_t)(m0 + row) * CDIM + k0 + colS, &ldsA[rowbase * 64]);
      load16_to_lds(Bt + (size_t)(n0 + row) * CDIM + k0 + colS, &ldsB[rowbase * 64]);
    }
    __syncthreads();

    bf16x8 fa[4][2], fb[4][2];
#pragma unroll
    for (int i = 0; i < 4; i++) {
      fa[i][0] = *(const bf16x8*)&ldsA[wr * 4096 + i * 1024 + rb0];
      fa[i][1] = *(const bf16x8*)&ldsA[wr * 4096 + i * 1024 + rb1];
    }
#pragma unroll
    for (int j = 0; j < 4; j++) {
      fb[j][0] = *(const bf16x8*)&ldsB[wc * 4096 + j * 1024 + rb0];
      fb[j][1] = *(const bf16x8*)&ldsB[wc * 4096 + j * 1024 + rb1];
    }

#pragma unroll
    for (int i = 0; i < 4; i++)
#pragma unroll
      for (int j = 0; j < 4; j++) {
        acc[i][j] = __builtin_amdgcn_mfma_f32_16x16x32_bf16(fa[i][0], fb[j][0], acc[i][j], 0, 0, 0);
        acc[i][j] = __builtin_amdgcn_mfma_f32_16x16x32_bf16(fa[i][1], fb[j][1], acc[i][j], 0, 0, 0);
      }
  }

#pragma unroll
  for (int i = 0; i < 4; i++) {
    const int row = m0 + wr * 64 + i * 16 + quad * 4;
#pragma unroll
    for (int j = 0; j < 4; j++) {
      const int col = n0 + wc * 64 + j * 16 + l16;
      const float bv2 = bias[col];
#pragma unroll
      for (int r = 0; r < 4; r++)
        Cmat[(size_t)(row + r) * CDIM + col] = acc[i][j][r] + bv2;
    }
  }
}

// ---------------------------------------------------------------------------
// MFMA causal flash attention, v11 — ADJACENT-PAIR wave scheduling.
// R12 change (6-line reindex of the verified v10 kernel, everything else
// byte-identical): wave m = p*4+wave handles q-tiles (2m, 2m+1) instead of
// (m', 63-m'). Both groups then share the SAME active range kt <= m
// (end = m+1 for both; dA/dB collapse to one bool), and block p needs only
// KT = 4p+4 iterations instead of ((63-4p)>>1)+1. Per-CU pair (p,7-p):
// staged tiles 36 vs 50 -> 28% fewer staging+barrier iterations, MFMA work
// conserved, per-CU balance exact (36 uniform), coverage bijective
// (2m,2m+1 over m in [0,32)). Accumulation order per q-row over kt
// unchanged -> bit-exact. Masking hits only the last active iteration
// (kt == m) for both groups.
// v10 base (VERIFIED R7-R11): conflict-free XOR-swizzled LDS, hoisted
// swizzle bases, reg-staged K/V dbuf, ONE barrier/iter, CU pairing remap.
// ---------------------------------------------------------------------------
__global__ __launch_bounds__(256, 2) void flash_attn_mfma(
    const unsigned short* __restrict__ Qb, const unsigned short* __restrict__ Kb,
    const unsigned short* __restrict__ vt, unsigned short* __restrict__ aout) {
  __shared__ unsigned short K_lds[2 * 64 * 64];     // double-buffered
  __shared__ unsigned short V_lds[2 * 64 * 64];     // double-buffered
  __shared__ unsigned short P_lds[4][2][32 * 64];   // [wave][group][32 rows]

  const int tid  = threadIdx.x;
  const int lane = tid & 63;
  const int wave = tid >> 6;          // 0..3
  const int id   = blockIdx.x;
  const int bh   = id & 63;           // XCD bucket; blocks id,id+256 share bh
  const int pr   = id >> 6;           // 0..7 raw
  const int p    = pr < 4 ? pr : 11 - pr;   // CU pairing: (0,7),(1,6),(2,5),(3,4)
  const int b    = bh >> 4, h = bh & 15;
  const int quad = lane >> 4;
  const int l16  = lane & 15;

  const int m    = p * 4 + wave;      // 0..31
  const int wqA  = m * 64;            // q-tile 2m
  const int wqB  = m * 64 + 32;       // q-tile 2m+1
  const int endW = m + 1;             // active range for BOTH groups
  const int KT   = 4 * p + 4;         // block-uniform iterations

  // ---- hoisted swizzle bases (kt-invariant) ----
  const int cx34   = (quad * 8) ^ ((l16 & 3) << 3);          // bits 3-4
  const int rb_ks0 = l16 * 64 + ((l16 & 4) << 3) + cx34;     // ks=0
  const int rb_ks1 = l16 * 64 + (32 ^ ((l16 & 4) << 3)) + cx34;  // ks=1
  int pwoff[4][4];
#pragma unroll
  for (int r = 0; r < 4; r++)
#pragma unroll
    for (int nt = 0; nt < 4; nt++)
      pwoff[r][nt] = (quad * 4 + r) * 64
                   + ((nt * 16) ^ (((quad & 1) << 5) | ((r & 2) << 3)))
                   + (l16 ^ ((r & 1) << 3));
  // staging write side
  const int srow = tid >> 2;          // 0..63
  const int scol = (tid & 3) * 16;    // 0,16,32,48
  const int ms   = (srow & 7) << 3;
  const int st0  = srow * 64 + (scol ^ ms);
  const int st1  = srow * 64 + ((scol + 8) ^ ms);

  // Q A-frags for both groups (Q pre-scaled by 0.125*log2e)
  bf16x8 aqA[2][2], aqB[2][2];
#pragma unroll
  for (int mt = 0; mt < 2; mt++)
#pragma unroll
    for (int ks = 0; ks < 2; ks++) {
      aqA[mt][ks] = *(const bf16x8*)(Qb + (size_t)(b * TSEQ + wqA + mt * 16 + l16) * CDIM
                                        + h * 64 + ks * 32 + quad * 8);
      aqB[mt][ks] = *(const bf16x8*)(Qb + (size_t)(b * TSEQ + wqB + mt * 16 + l16) * CDIM
                                        + h * 64 + ks * 32 + quad * 8);
    }

  f32x4 OA[2][4] = {}, OB[2][4] = {};
  f32x4 lA[2] = {}, lB[2] = {};

  bf16x8 ones;
#pragma unroll
  for (int jj = 0; jj < 8; jj++) ones[jj] = (__bf16)1.0f;

  const unsigned short* Kg = Kb + (size_t)b * TSEQ * CDIM + h * 64;
  const unsigned short* Vg = vt + (size_t)bh * 64 * TSEQ;
  unsigned short* pwA = &P_lds[wave][0][0];
  unsigned short* pwB = &P_lds[wave][1][0];

  // preload tile 0 into staging registers
  uint4 kr0, kr1, vr0, vr1;
  {
    const uint4* ks_ = (const uint4*)(Kg + (size_t)srow * CDIM + scol);
    kr0 = ks_[0]; kr1 = ks_[1];
    const uint4* vs_ = (const uint4*)(Vg + (size_t)srow * TSEQ + scol);
    vr0 = vs_[0]; vr1 = vs_[1];
  }

  for (int kt = 0; kt < KT; kt++) {
    const int kbase = kt * 64;
    const int bo    = (kt & 1) << 12;    // double-buffer offset (u16 units)

    *(uint4*)&K_lds[bo + st0] = kr0;
    *(uint4*)&K_lds[bo + st1] = kr1;
    *(uint4*)&V_lds[bo + st0] = vr0;
    *(uint4*)&V_lds[bo + st1] = vr1;
    __syncthreads();   // staged tile visible; ONE barrier per iteration

    if (kt + 1 < KT) {
      const uint4* ks_ = (const uint4*)(Kg + (size_t)(kbase + 64 + srow) * CDIM + scol);
      kr0 = ks_[0]; kr1 = ks_[1];
      const uint4* vs_ = (const uint4*)(Vg + (size_t)srow * TSEQ + kbase + 64 + scol);
      vr0 = vs_[0]; vr1 = vs_[1];
    }

    const bool d = (kt < endW);      // both groups share the active range

    if (d) {
      // ---- S phase (both groups) ----
      f32x4 SA[2][4] = {}, SB[2][4] = {};
#pragma unroll
      for (int nt = 0; nt < 4; nt++)
#pragma unroll
        for (int ks = 0; ks < 2; ks++) {
          bf16x8 bk = *(const bf16x8*)&K_lds[bo + nt * 1024 + (ks ? rb_ks1 : rb_ks0)];
          SA[0][nt] = __builtin_amdgcn_mfma_f32_16x16x32_bf16(aqA[0][ks], bk, SA[0][nt], 0, 0, 0);
          SA[1][nt] = __builtin_amdgcn_mfma_f32_16x16x32_bf16(aqA[1][ks], bk, SA[1][nt], 0, 0, 0);
          SB[0][nt] = __builtin_amdgcn_mfma_f32_16x16x32_bf16(aqB[0][ks], bk, SB[0][nt], 0, 0, 0);
          SB[1][nt] = __builtin_amdgcn_mfma_f32_16x16x32_bf16(aqB[1][ks], bk, SB[1][nt], 0, 0, 0);
        }

      // ---- P phase (exp2; mask only on the diagonal iteration kt==m) ----
      {
        const bool maskedA = (kbase + 64 > wqA);
#pragma unroll
        for (int mt = 0; mt < 2; mt++) {
#pragma unroll
          for (int nt = 0; nt < 4; nt++)
#pragma unroll
            for (int r = 0; r < 4; r += 2) {
              float s0 = SA[mt][nt][r], s1 = SA[mt][nt][r + 1];
              if (maskedA) {
                const int qrow = wqA + mt * 16 + quad * 4 + r;
                const int key  = kbase + nt * 16 + l16;
                s0 = (key <= qrow)     ? s0 : -1e30f;
                s1 = (key <= qrow + 1) ? s1 : -1e30f;
              }
              __hip_bfloat162 p2 = __float22bfloat162_rn(make_float2(EXP2F(s0), EXP2F(s1)));
              unsigned int u; __builtin_memcpy(&u, &p2, 4);
              pwA[pwoff[r    ][nt] + mt * 1024] = (unsigned short)u;
              pwA[pwoff[r + 1][nt] + mt * 1024] = (unsigned short)(u >> 16);
            }
        }
      }
      {
        const bool maskedB = (kbase + 64 > wqB);
#pragma unroll
        for (int mt = 0; mt < 2; mt++) {
#pragma unroll
          for (int nt = 0; nt < 4; nt++)
#pragma unroll
            for (int r = 0; r < 4; r += 2) {
              float s0 = SB[mt][nt][r], s1 = SB[mt][nt][r + 1];
              if (maskedB) {
                const int qrow = wqB + mt * 16 + quad * 4 + r;
                const int key  = kbase + nt * 16 + l16;
                s0 = (key <= qrow)     ? s0 : -1e30f;
                s1 = (key <= qrow + 1) ? s1 : -1e30f;
              }
              __hip_bfloat162 p2 = __float22bfloat162_rn(make_float2(EXP2F(s0), EXP2F(s1)));
              unsigned int u; __builtin_memcpy(&u, &p2, 4);
              pwB[pwoff[r    ][nt] + mt * 1024] = (unsigned short)u;
              pwB[pwoff[r + 1][nt] + mt * 1024] = (unsigned short)(u >> 16);
            }
        }
      }

      // ---- O phase (both groups) ----
#pragma unroll
      for (int ks = 0; ks < 2; ks++) {
        const int rb = ks ? rb_ks1 : rb_ks0;
        bf16x8 bv[4];
#pragma unroll
        for (int nt = 0; nt < 4; nt++)
          bv[nt] = *(const bf16x8*)&V_lds[bo + nt * 1024 + rb];
#pragma unroll
        for (int mt = 0; mt < 2; mt++) {
          bf16x8 ap = *(const bf16x8*)&pwA[mt * 1024 + rb];
          lA[mt] = __builtin_amdgcn_mfma_f32_16x16x32_bf16(ap, ones, lA[mt], 0, 0, 0);
#pragma unroll
          for (int nt = 0; nt < 4; nt++)
            OA[mt][nt] = __builtin_amdgcn_mfma_f32_16x16x32_bf16(ap, bv[nt], OA[mt][nt], 0, 0, 0);
        }
#pragma unroll
        for (int mt = 0; mt < 2; mt++) {
          bf16x8 ap = *(const bf16x8*)&pwB[mt * 1024 + rb];
          lB[mt] = __builtin_amdgcn_mfma_f32_16x16x32_bf16(ap, ones, lB[mt], 0, 0, 0);
#pragma unroll
          for (int nt = 0; nt < 4; nt++)
            OB[mt][nt] = __builtin_amdgcn_mfma_f32_16x16x32_bf16(ap, bv[nt], OB[mt][nt], 0, 0, 0);
        }
      }
    }
  }

  // epilogue: O / l -> aout [b t][h d], both groups
#pragma unroll
  for (int mt = 0; mt < 2; mt++) {
    float invA[4], invB[4];
#pragma unroll
    for (int r = 0; r < 4; r++) { invA[r] = 1.0f / lA[mt][r]; invB[r] = 1.0f / lB[mt][r]; }
    unsigned short* oa = aout + (size_t)(b * TSEQ + wqA + mt * 16 + quad * 4) * CDIM + h * 64 + l16;
    unsigned short* ob = aout + (size_t)(b * TSEQ + wqB + mt * 16 + quad * 4) * CDIM + h * 64 + l16;
#pragma unroll
    for (int nt = 0; nt < 4; nt++)
#pragma unroll
      for (int r = 0; r < 4; r++) {
        oa[(size_t)r * CDIM + nt * 16] = f2bf(OA[mt][nt][r] * invA[r]);
        ob[(size_t)r * CDIM + nt * 16] = f2bf(OB[mt][nt][r] * invB[r]);
      }
  }
}

// ---------------------------------------------------------------------------
extern "C" void kernel_launch(void* const* d_in, const int* in_sizes, int n_in,
                              void* d_out, int out_size, void* d_ws, size_t ws_size,
                              hipStream_t stream) {
  (void)in_sizes; (void)n_in; (void)out_size;
  const float* x     = (const float*)d_in[0];  // [8192,1024] fp32
  const float* w_qkv = (const float*)d_in[1];  // [1024,3072] fp32
  const float* w_out = (const float*)d_in[2];  // [1024,1024] fp32
  const float* b_out = (const float*)d_in[3];  // [1024] fp32
  float* out = (float*)d_out;                  // [8192,1024] fp32

  // Workspace: 72 MiB. Layout (R9): Qb@0, Kb@16M, vt@32M, xb@48M,
  // aout@48M (aliases xb, dead after gemm_qkv), wqkvT@64M, woutT@70M.
  const size_t WS_NEED = 75497472;
  if (ws_size < WS_NEED) return;

  char* ws = (char*)d_ws;
  unsigned short* Qb    = (unsigned short*)(ws);
  unsigned short* Kb    = (unsigned short*)(ws + 16777216);
  unsigned short* vt    = (unsigned short*)(ws + 33554432);
  unsigned short* xb    = (unsigned short*)(ws + 50331648);
  unsigned short* aout  = (unsigned short*)(ws + 50331648);  // alias of xb
  unsigned short* wqkvT = (unsigned short*)(ws + 67108864);
  unsigned short* woutT = (unsigned short*)(ws + 73400320);

  // 1) merged prep: x->bf16 + both weight transposes (one launch)
  prep_all<<<dim3(4096 + 768 + 256), 256, 0, stream>>>(
      x, xb, w_qkv, wqkvT, w_out, woutT);

  // 2) QKV projection (Q pre-scaled 0.125*log2e); V written directly as vt
  gemm_qkv<<<dim3(QKVCOL / 128, MROWS / 128), 256, 0, stream>>>(xb, wqkvT, Qb, Kb, vt);

  // 3) adjacent-pair balanced MFMA flash attention -> aout (overwrites xb)
  flash_attn_mfma<<<dim3(8 * 64), 256, 0, stream>>>(Qb, Kb, vt, aout);

  // 4) out-projection + bias
  gemm_out<<<dim3(CDIM / 128, MROWS / 128), 256, 0, stream>>>(aout, woutT, out, b_out);
}

// Round 13
// 253.809 us; speedup vs baseline: 1.0401x; 1.0401x over previous
//
#include <hip/hip_runtime.h>
#include <hip/hip_bf16.h>

// Shapes (fixed by the problem)
#define BATCH  4
#define TSEQ   2048
#define CDIM   1024
#define NHEAD  16
#define DHEAD  64
#define MROWS  (BATCH * TSEQ)      // 8192
#define QKVCOL (3 * CDIM)          // 3072

typedef __bf16 bf16x8 __attribute__((ext_vector_type(8)));
typedef float  f32x4  __attribute__((ext_vector_type(4)));

// hardware exp2 (v_exp_f32). __exp2f collides with a glibc macro (R12).
#define EXP2F(x) __builtin_amdgcn_exp2f(x)

__device__ __forceinline__ unsigned short f2bf(float f) {
  union { float f; unsigned int i; } v; v.f = f;
  unsigned int i = v.i;
  return (unsigned short)((i + 0x7fffu + ((i >> 16) & 1u)) >> 16);  // RNE
}

__device__ __forceinline__ void load16_to_lds(const void* g, void* l) {
  __builtin_amdgcn_global_load_lds(
      (const __attribute__((address_space(1))) unsigned int*)g,
      (__attribute__((address_space(3))) unsigned int*)l, 16, 0, 0);
}

// ---------------------------------------------------------------------------
// prep_all (VERIFIED R11): cast x->bf16 + transpose_cast(w_qkv) +
// transpose_cast(w_out) merged into ONE launch. UNCHANGED.
// ---------------------------------------------------------------------------
__global__ __launch_bounds__(256) void prep_all(
    const float* __restrict__ x,     unsigned short* __restrict__ xb,
    const float* __restrict__ w_qkv, unsigned short* __restrict__ wqkvT,
    const float* __restrict__ w_out, unsigned short* __restrict__ woutT) {
  __shared__ float tile[64][68];
  const int id = blockIdx.x;
  const int t  = threadIdx.x;

  if (id < 4096) {
    // ---- cast x -> bf16 (8 elems/thread) ----
    const int i = (id * 256 + t) * 8;
    float4 a = *(const float4*)(x + i);
    float4 b = *(const float4*)(x + i + 4);
    unsigned short v[8] = {f2bf(a.x), f2bf(a.y), f2bf(a.z), f2bf(a.w),
                           f2bf(b.x), f2bf(b.y), f2bf(b.z), f2bf(b.w)};
    *(uint4*)(xb + i) = *(const uint4*)v;
    return;
  }

  // ---- transpose+cast a weight matrix: fp32 [R=1024, C] -> bf16 [C, 1024] ----
  const float* in;
  unsigned short* out;
  int C, bx, by;
  if (id < 4096 + 768) {
    const int t1 = id - 4096;
    in = w_qkv; out = wqkvT; C = QKVCOL;
    bx = t1 % 48; by = t1 / 48;
  } else {
    const int t2 = id - 4096 - 768;
    in = w_out; out = woutT; C = CDIM;
    bx = t2 & 15; by = t2 >> 4;
  }
  const int R  = CDIM;
  const int r0 = by * 64;
  const int c0 = bx * 64;
  const int tr = t >> 2;
  const int tc = (t & 3) * 16;

  const float4* src = (const float4*)(in + (size_t)(r0 + tr) * C + c0 + tc);
#pragma unroll
  for (int i = 0; i < 4; i++)
    *(float4*)&tile[tr][tc + 4 * i] = src[i];
  __syncthreads();

  unsigned short vals[16];
#pragma unroll
  for (int k = 0; k < 16; k++) vals[k] = f2bf(tile[tc + k][tr]);
  uint4* dst = (uint4*)(out + (size_t)(c0 + tr) * R + r0 + tc);
  dst[0] = ((const uint4*)vals)[0];
  dst[1] = ((const uint4*)vals)[1];
}

// ---------------------------------------------------------------------------
// QKV GEMM, BK=64 swizzled staging — VERIFIED R9/R11 (~77µs, absmax
// 0.015625, 0 conflicts). V^T fused epilogue + Q scale 0.125*log2(e).
// UNCHANGED.
// ---------------------------------------------------------------------------
__global__ __launch_bounds__(256) void gemm_qkv(
    const unsigned short* __restrict__ A, const unsigned short* __restrict__ Bt,
    unsigned short* __restrict__ Qb, unsigned short* __restrict__ Kb,
    unsigned short* __restrict__ vt) {
  __shared__ unsigned short ldsA[128 * 64];
  __shared__ unsigned short ldsB[128 * 64];

  const int tid  = threadIdx.x;
  const int lane = tid & 63;
  const int wave = tid >> 6;
  const int m0   = blockIdx.y * 128;
  const int n0   = blockIdx.x * 128;
  const int wr   = wave >> 1;
  const int wc   = wave & 1;
  const int quad = lane >> 4;
  const int l16  = lane & 15;

  f32x4 acc[4][4] = {};
  const int rsub = lane >> 3;          // 0..7   (row within 8-row chunk)
  const int csub = (lane & 7) * 8;     // 0..56  (col granule)

  // hoisted conflict-free read bases (v7 formulas, 64-elem rows)
  const int cx34 = (quad * 8) ^ ((l16 & 3) << 3);
  const int rb0  = l16 * 64 + ((l16 & 4) << 3) + cx34;          // ks=0
  const int rb1  = l16 * 64 + (32 ^ ((l16 & 4) << 3)) + cx34;   // ks=1

  for (int k0 = 0; k0 < CDIM; k0 += 64) {
    __syncthreads();
#pragma unroll
    for (int i = 0; i < 4; i++) {
      const int rowbase = i * 32 + wave * 8;
      const int row  = rowbase + rsub;
      const int colS = csub ^ ((row & 7) * 8);   // pre-swizzled source
      load16_to_lds(A  + (size_t)(m0 + row) * CDIM + k0 + colS, &ldsA[rowbase * 64]);
      load16_to_lds(Bt + (size_t)(n0 + row) * CDIM + k0 + colS, &ldsB[rowbase * 64]);
    }
    __syncthreads();

    bf16x8 fa[4][2], fb[4][2];
#pragma unroll
    for (int i = 0; i < 4; i++) {
      fa[i][0] = *(const bf16x8*)&ldsA[wr * 4096 + i * 1024 + rb0];
      fa[i][1] = *(const bf16x8*)&ldsA[wr * 4096 + i * 1024 + rb1];
    }
#pragma unroll
    for (int j = 0; j < 4; j++) {
      fb[j][0] = *(const bf16x8*)&ldsB[wc * 4096 + j * 1024 + rb0];
      fb[j][1] = *(const bf16x8*)&ldsB[wc * 4096 + j * 1024 + rb1];
    }

#pragma unroll
    for (int i = 0; i < 4; i++)
#pragma unroll
      for (int j = 0; j < 4; j++) {
        acc[i][j] = __builtin_amdgcn_mfma_f32_16x16x32_bf16(fa[i][0], fb[j][0], acc[i][j], 0, 0, 0);
        acc[i][j] = __builtin_amdgcn_mfma_f32_16x16x32_bf16(fa[i][1], fb[j][1], acc[i][j], 0, 0, 0);
      }
  }

  const int seg = n0 >> 10;                       // 0=Q 1=K 2=V
  if (seg == 2) {
    // V: write directly transposed into vt [b*16+h][d][t] (bit-exact values)
#pragma unroll
    for (int i = 0; i < 4; i++) {
      const int row = m0 + wr * 64 + i * 16 + quad * 4;   // = b*2048 + t0
      const int bb  = row >> 11;
      const int t0  = row & 2047;                          // t0 % 4 == 0
#pragma unroll
      for (int j = 0; j < 4; j++) {
        const int col = ((n0 & 1023) + wc * 64 + j * 16 + l16);  // h*64+d
        unsigned short v4[4];
#pragma unroll
        for (int r = 0; r < 4; r++) v4[r] = f2bf(acc[i][j][r]);
        *(uint2*)(vt + ((size_t)(bb * 16 + (col >> 6)) * 64 + (col & 63)) * TSEQ + t0)
            = *(const uint2*)v4;
      }
    }
  } else {
    unsigned short* dst = seg == 0 ? Qb : Kb;
    const float scl = seg == 0 ? 0.18033688f : 1.0f;  // 0.125*log2(e)
#pragma unroll
    for (int i = 0; i < 4; i++) {
      const int row = m0 + wr * 64 + i * 16 + quad * 4;
#pragma unroll
      for (int j = 0; j < 4; j++) {
        const int col = ((n0 & 1023) + wc * 64 + j * 16 + l16);
#pragma unroll
        for (int r = 0; r < 4; r++)
          dst[(size_t)(row + r) * CDIM + col] = f2bf(acc[i][j][r] * scl);
      }
    }
  }
}

// ---------------------------------------------------------------------------
// Out-projection GEMM, BK=64 swizzled staging — VERIFIED R9/R11. UNCHANGED.
// ---------------------------------------------------------------------------
__global__ __launch_bounds__(256) void gemm_out(
    const unsigned short* __restrict__ A, const unsigned short* __restrict__ Bt,
    float* __restrict__ Cmat, const float* __restrict__ bias) {
  __shared__ unsigned short ldsA[128 * 64];
  __shared__ unsigned short ldsB[128 * 64];

  const int tid  = threadIdx.x;
  const int lane = tid & 63;
  const int wave = tid >> 6;
  const int m0   = blockIdx.y * 128;
  const int n0   = blockIdx.x * 128;
  const int wr   = wave >> 1;
  const int wc   = wave & 1;
  const int quad = lane >> 4;
  const int l16  = lane & 15;

  f32x4 acc[4][4] = {};
  const int rsub = lane >> 3;
  const int csub = (lane & 7) * 8;

  const int cx34 = (quad * 8) ^ ((l16 & 3) << 3);
  const int rb0  = l16 * 64 + ((l16 & 4) << 3) + cx34;
  const int rb1  = l16 * 64 + (32 ^ ((l16 & 4) << 3)) + cx34;

  for (int k0 = 0; k0 < CDIM; k0 += 64) {
    __syncthreads();
#pragma unroll
    for (int i = 0; i < 4; i++) {
      const int rowbase = i * 32 + wave * 8;
      const int row  = rowbase + rsub;
      const int colS = csub ^ ((row & 7) * 8);
      load16_to_lds(A  + (size_t)(m0 + row) * CDIM + k0 + colS, &ldsA[rowbase * 64]);
      load16_to_lds(Bt + (size_t)(n0 + row) * CDIM + k0 + colS, &ldsB[rowbase * 64]);
    }
    __syncthreads();

    bf16x8 fa[4][2], fb[4][2];
#pragma unroll
    for (int i = 0; i < 4; i++) {
      fa[i][0] = *(const bf16x8*)&ldsA[wr * 4096 + i * 1024 + rb0];
      fa[i][1] = *(const bf16x8*)&ldsA[wr * 4096 + i * 1024 + rb1];
    }
#pragma unroll
    for (int j = 0; j < 4; j++) {
      fb[j][0] = *(const bf16x8*)&ldsB[wc * 4096 + j * 1024 + rb0];
      fb[j][1] = *(const bf16x8*)&ldsB[wc * 4096 + j * 1024 + rb1];
    }

#pragma unroll
    for (int i = 0; i < 4; i++)
#pragma unroll
      for (int j = 0; j < 4; j++) {
        acc[i][j] = __builtin_amdgcn_mfma_f32_16x16x32_bf16(fa[i][0], fb[j][0], acc[i][j], 0, 0, 0);
        acc[i][j] = __builtin_amdgcn_mfma_f32_16x16x32_bf16(fa[i][1], fb[j][1], acc[i][j], 0, 0, 0);
      }
  }

#pragma unroll
  for (int i = 0; i < 4; i++) {
    const int row = m0 + wr * 64 + i * 16 + quad * 4;
#pragma unroll
    for (int j = 0; j < 4; j++) {
      const int col = n0 + wc * 64 + j * 16 + l16;
      const float bv2 = bias[col];
#pragma unroll
      for (int r = 0; r < 4; r++)
        Cmat[(size_t)(row + r) * CDIM + col] = acc[i][j][r] + bv2;
    }
  }
}

// ---------------------------------------------------------------------------
// MFMA causal flash attention, v10 — VERIFIED R7/R8/R9/R11 (~75-76µs,
// absmax 0.015625, 0 bank conflicts) = v7 structure + CU load-balance remap.
// R12's adjacent-pair variant REVERTED: per-CU block pair became (KT=4,
// KT=32-full-work) -> occupancy 19->12.8%, flash 76->84µs. The (j,63-j)
// per-wave pairing keeps every wave active for ~the whole block duration;
// both neighboring schedules (v8 split, v11 adjacent) measured worse.
// ---------------------------------------------------------------------------
__global__ __launch_bounds__(256, 2) void flash_attn_mfma(
    const unsigned short* __restrict__ Qb, const unsigned short* __restrict__ Kb,
    const unsigned short* __restrict__ vt, unsigned short* __restrict__ aout) {
  __shared__ unsigned short K_lds[2 * 64 * 64];     // double-buffered
  __shared__ unsigned short V_lds[2 * 64 * 64];     // double-buffered
  __shared__ unsigned short P_lds[4][2][32 * 64];   // [wave][group][32 rows]

  const int tid  = threadIdx.x;
  const int lane = tid & 63;
  const int wave = tid >> 6;          // 0..3
  const int id   = blockIdx.x;
  const int bh   = id & 63;           // XCD bucket; blocks id,id+256 share bh
  const int pr   = id >> 6;           // 0..7 raw
  const int p    = pr < 4 ? pr : 11 - pr;   // balance remap: pairs sum 50/50/50/50
  const int b    = bh >> 4, h = bh & 15;
  const int quad = lane >> 4;
  const int l16  = lane & 15;

  const int j    = p * 4 + wave;      // 0..31
  const int wqA  = j * 32;
  const int wqB  = (63 - j) * 32;
  const int endA = (wqA >> 6) + 1;    // active tiles for group A
  const int endB = (wqB >> 6) + 1;
  const int KT   = ((63 - 4 * p) >> 1) + 1;   // block-uniform iterations

  // ---- hoisted swizzle bases (kt-invariant) ----
  const int cx34   = (quad * 8) ^ ((l16 & 3) << 3);          // bits 3-4
  const int rb_ks0 = l16 * 64 + ((l16 & 4) << 3) + cx34;     // ks=0
  const int rb_ks1 = l16 * 64 + (32 ^ ((l16 & 4) << 3)) + cx34;  // ks=1
  int pwoff[4][4];
#pragma unroll
  for (int r = 0; r < 4; r++)
#pragma unroll
    for (int nt = 0; nt < 4; nt++)
      pwoff[r][nt] = (quad * 4 + r) * 64
                   + ((nt * 16) ^ (((quad & 1) << 5) | ((r & 2) << 3)))
                   + (l16 ^ ((r & 1) << 3));
  // staging write side
  const int srow = tid >> 2;          // 0..63
  const int scol = (tid & 3) * 16;    // 0,16,32,48
  const int ms   = (srow & 7) << 3;
  const int st0  = srow * 64 + (scol ^ ms);
  const int st1  = srow * 64 + ((scol + 8) ^ ms);

  // Q A-frags for both groups (Q pre-scaled by 0.125*log2e)
  bf16x8 aqA[2][2], aqB[2][2];
#pragma unroll
  for (int mt = 0; mt < 2; mt++)
#pragma unroll
    for (int ks = 0; ks < 2; ks++) {
      aqA[mt][ks] = *(const bf16x8*)(Qb + (size_t)(b * TSEQ + wqA + mt * 16 + l16) * CDIM
                                        + h * 64 + ks * 32 + quad * 8);
      aqB[mt][ks] = *(const bf16x8*)(Qb + (size_t)(b * TSEQ + wqB + mt * 16 + l16) * CDIM
                                        + h * 64 + ks * 32 + quad * 8);
    }

  f32x4 OA[2][4] = {}, OB[2][4] = {};
  f32x4 lA[2] = {}, lB[2] = {};

  bf16x8 ones;
#pragma unroll
  for (int jj = 0; jj < 8; jj++) ones[jj] = (__bf16)1.0f;

  const unsigned short* Kg = Kb + (size_t)b * TSEQ * CDIM + h * 64;
  const unsigned short* Vg = vt + (size_t)bh * 64 * TSEQ;
  unsigned short* pwA = &P_lds[wave][0][0];
  unsigned short* pwB = &P_lds[wave][1][0];

  // preload tile 0 into staging registers
  uint4 kr0, kr1, vr0, vr1;
  {
    const uint4* ks_ = (const uint4*)(Kg + (size_t)srow * CDIM + scol);
    kr0 = ks_[0]; kr1 = ks_[1];
    const uint4* vs_ = (const uint4*)(Vg + (size_t)srow * TSEQ + scol);
    vr0 = vs_[0]; vr1 = vs_[1];
  }

  for (int kt = 0; kt < KT; kt++) {
    const int kbase = kt * 64;
    const int bo    = (kt & 1) << 12;    // double-buffer offset (u16 units)

    *(uint4*)&K_lds[bo + st0] = kr0;
    *(uint4*)&K_lds[bo + st1] = kr1;
    *(uint4*)&V_lds[bo + st0] = vr0;
    *(uint4*)&V_lds[bo + st1] = vr1;
    __syncthreads();   // staged tile visible; ONE barrier per iteration

    if (kt + 1 < KT) {
      const uint4* ks_ = (const uint4*)(Kg + (size_t)(kbase + 64 + srow) * CDIM + scol);
      kr0 = ks_[0]; kr1 = ks_[1];
      const uint4* vs_ = (const uint4*)(Vg + (size_t)srow * TSEQ + kbase + 64 + scol);
      vr0 = vs_[0]; vr1 = vs_[1];
    }

    const bool dA = (kt < endA);
    const bool dB = (kt < endB);

    // ---- S phase (both groups) ----
    f32x4 SA[2][4] = {}, SB[2][4] = {};
#pragma unroll
    for (int nt = 0; nt < 4; nt++)
#pragma unroll
      for (int ks = 0; ks < 2; ks++) {
        bf16x8 bk = *(const bf16x8*)&K_lds[bo + nt * 1024 + (ks ? rb_ks1 : rb_ks0)];
        if (dA) {
          SA[0][nt] = __builtin_amdgcn_mfma_f32_16x16x32_bf16(aqA[0][ks], bk, SA[0][nt], 0, 0, 0);
          SA[1][nt] = __builtin_amdgcn_mfma_f32_16x16x32_bf16(aqA[1][ks], bk, SA[1][nt], 0, 0, 0);
        }
        if (dB) {
          SB[0][nt] = __builtin_amdgcn_mfma_f32_16x16x32_bf16(aqB[0][ks], bk, SB[0][nt], 0, 0, 0);
          SB[1][nt] = __builtin_amdgcn_mfma_f32_16x16x32_bf16(aqB[1][ks], bk, SB[1][nt], 0, 0, 0);
        }
      }

    // ---- P phase (exp2; mask only on diagonal tiles) ----
    if (dA) {
      const bool maskedA = (kbase + 64 > wqA);
#pragma unroll
      for (int mt = 0; mt < 2; mt++) {
#pragma unroll
        for (int nt = 0; nt < 4; nt++)
#pragma unroll
          for (int r = 0; r < 4; r += 2) {
            float s0 = SA[mt][nt][r], s1 = SA[mt][nt][r + 1];
            if (maskedA) {
              const int qrow = wqA + mt * 16 + quad * 4 + r;
              const int key  = kbase + nt * 16 + l16;
              s0 = (key <= qrow)     ? s0 : -1e30f;
              s1 = (key <= qrow + 1) ? s1 : -1e30f;
            }
            __hip_bfloat162 p2 = __float22bfloat162_rn(make_float2(EXP2F(s0), EXP2F(s1)));
            unsigned int u; __builtin_memcpy(&u, &p2, 4);
            pwA[pwoff[r    ][nt] + mt * 1024] = (unsigned short)u;
            pwA[pwoff[r + 1][nt] + mt * 1024] = (unsigned short)(u >> 16);
          }
      }
    }
    if (dB) {
      const bool maskedB = (kbase + 64 > wqB);
#pragma unroll
      for (int mt = 0; mt < 2; mt++) {
#pragma unroll
        for (int nt = 0; nt < 4; nt++)
#pragma unroll
          for (int r = 0; r < 4; r += 2) {
            float s0 = SB[mt][nt][r], s1 = SB[mt][nt][r + 1];
            if (maskedB) {
              const int qrow = wqB + mt * 16 + quad * 4 + r;
              const int key  = kbase + nt * 16 + l16;
              s0 = (key <= qrow)     ? s0 : -1e30f;
              s1 = (key <= qrow + 1) ? s1 : -1e30f;
            }
            __hip_bfloat162 p2 = __float22bfloat162_rn(make_float2(EXP2F(s0), EXP2F(s1)));
            unsigned int u; __builtin_memcpy(&u, &p2, 4);
            pwB[pwoff[r    ][nt] + mt * 1024] = (unsigned short)u;
            pwB[pwoff[r + 1][nt] + mt * 1024] = (unsigned short)(u >> 16);
          }
      }
    }

    // ---- O phase (both groups) ----
#pragma unroll
    for (int ks = 0; ks < 2; ks++) {
      const int rb = ks ? rb_ks1 : rb_ks0;
      bf16x8 bv[4];
#pragma unroll
      for (int nt = 0; nt < 4; nt++)
        bv[nt] = *(const bf16x8*)&V_lds[bo + nt * 1024 + rb];
      if (dA) {
#pragma unroll
        for (int mt = 0; mt < 2; mt++) {
          bf16x8 ap = *(const bf16x8*)&pwA[mt * 1024 + rb];
          lA[mt] = __builtin_amdgcn_mfma_f32_16x16x32_bf16(ap, ones, lA[mt], 0, 0, 0);
#pragma unroll
          for (int nt = 0; nt < 4; nt++)
            OA[mt][nt] = __builtin_amdgcn_mfma_f32_16x16x32_bf16(ap, bv[nt], OA[mt][nt], 0, 0, 0);
        }
      }
      if (dB) {
#pragma unroll
        for (int mt = 0; mt < 2; mt++) {
          bf16x8 ap = *(const bf16x8*)&pwB[mt * 1024 + rb];
          lB[mt] = __builtin_amdgcn_mfma_f32_16x16x32_bf16(ap, ones, lB[mt], 0, 0, 0);
#pragma unroll
          for (int nt = 0; nt < 4; nt++)
            OB[mt][nt] = __builtin_amdgcn_mfma_f32_16x16x32_bf16(ap, bv[nt], OB[mt][nt], 0, 0, 0);
        }
      }
    }
  }

  // epilogue: O / l -> aout [b t][h d], both groups
#pragma unroll
  for (int mt = 0; mt < 2; mt++) {
    float invA[4], invB[4];
#pragma unroll
    for (int r = 0; r < 4; r++) { invA[r] = 1.0f / lA[mt][r]; invB[r] = 1.0f / lB[mt][r]; }
    unsigned short* oa = aout + (size_t)(b * TSEQ + wqA + mt * 16 + quad * 4) * CDIM + h * 64 + l16;
    unsigned short* ob = aout + (size_t)(b * TSEQ + wqB + mt * 16 + quad * 4) * CDIM + h * 64 + l16;
#pragma unroll
    for (int nt = 0; nt < 4; nt++)
#pragma unroll
      for (int r = 0; r < 4; r++) {
        oa[(size_t)r * CDIM + nt * 16] = f2bf(OA[mt][nt][r] * invA[r]);
        ob[(size_t)r * CDIM + nt * 16] = f2bf(OB[mt][nt][r] * invB[r]);
      }
  }
}

// ---------------------------------------------------------------------------
extern "C" void kernel_launch(void* const* d_in, const int* in_sizes, int n_in,
                              void* d_out, int out_size, void* d_ws, size_t ws_size,
                              hipStream_t stream) {
  (void)in_sizes; (void)n_in; (void)out_size;
  const float* x     = (const float*)d_in[0];  // [8192,1024] fp32
  const float* w_qkv = (const float*)d_in[1];  // [1024,3072] fp32
  const float* w_out = (const float*)d_in[2];  // [1024,1024] fp32
  const float* b_out = (const float*)d_in[3];  // [1024] fp32
  float* out = (float*)d_out;                  // [8192,1024] fp32

  // Workspace: 72 MiB. Layout (R9): Qb@0, Kb@16M, vt@32M, xb@48M,
  // aout@48M (aliases xb, dead after gemm_qkv), wqkvT@64M, woutT@70M.
  const size_t WS_NEED = 75497472;
  if (ws_size < WS_NEED) return;

  char* ws = (char*)d_ws;
  unsigned short* Qb    = (unsigned short*)(ws);
  unsigned short* Kb    = (unsigned short*)(ws + 16777216);
  unsigned short* vt    = (unsigned short*)(ws + 33554432);
  unsigned short* xb    = (unsigned short*)(ws + 50331648);
  unsigned short* aout  = (unsigned short*)(ws + 50331648);  // alias of xb
  unsigned short* wqkvT = (unsigned short*)(ws + 67108864);
  unsigned short* woutT = (unsigned short*)(ws + 73400320);

  // 1) merged prep: x->bf16 + both weight transposes (one launch)
  prep_all<<<dim3(4096 + 768 + 256), 256, 0, stream>>>(
      x, xb, w_qkv, wqkvT, w_out, woutT);

  // 2) QKV projection (Q pre-scaled 0.125*log2e); V written directly as vt
  gemm_qkv<<<dim3(QKVCOL / 128, MROWS / 128), 256, 0, stream>>>(xb, wqkvT, Qb, Kb, vt);

  // 3) balanced block-shared MFMA flash attention -> aout (overwrites xb)
  flash_attn_mfma<<<dim3(8 * 64), 256, 0, stream>>>(Qb, Kb, vt, aout);

  // 4) out-projection + bias
  gemm_out<<<dim3(CDIM / 128, MROWS / 128), 256, 0, stream>>>(aout, woutT, out, b_out);
}

// Round 14
// 249.843 us; speedup vs baseline: 1.0566x; 1.0159x over previous
//
#include <hip/hip_runtime.h>
#include <hip/hip_bf16.h>

// Shapes (fixed by the problem)
#define BATCH  4
#define TSEQ   2048
#define CDIM   1024
#define NHEAD  16
#define DHEAD  64
#define MROWS  (BATCH * TSEQ)      // 8192
#define QKVCOL (3 * CDIM)          // 3072

typedef __bf16 bf16x8 __attribute__((ext_vector_type(8)));
typedef float  f32x4  __attribute__((ext_vector_type(4)));

// hardware exp2 (v_exp_f32). __exp2f collides with a glibc macro (R12).
#define EXP2F(x) __builtin_amdgcn_exp2f(x)

__device__ __forceinline__ unsigned short f2bf(float f) {
  union { float f; unsigned int i; } v; v.f = f;
  unsigned int i = v.i;
  return (unsigned short)((i + 0x7fffu + ((i >> 16) & 1u)) >> 16);  // RNE
}

__device__ __forceinline__ void load16_to_lds(const void* g, void* l) {
  __builtin_amdgcn_global_load_lds(
      (const __attribute__((address_space(1))) unsigned int*)g,
      (__attribute__((address_space(3))) unsigned int*)l, 16, 0, 0);
}

// ---------------------------------------------------------------------------
// prep_all (VERIFIED R11): cast x->bf16 + transpose_cast(w_qkv) +
// transpose_cast(w_out) merged into ONE launch. UNCHANGED.
// ---------------------------------------------------------------------------
__global__ __launch_bounds__(256) void prep_all(
    const float* __restrict__ x,     unsigned short* __restrict__ xb,
    const float* __restrict__ w_qkv, unsigned short* __restrict__ wqkvT,
    const float* __restrict__ w_out, unsigned short* __restrict__ woutT) {
  __shared__ float tile[64][68];
  const int id = blockIdx.x;
  const int t  = threadIdx.x;

  if (id < 4096) {
    // ---- cast x -> bf16 (8 elems/thread) ----
    const int i = (id * 256 + t) * 8;
    float4 a = *(const float4*)(x + i);
    float4 b = *(const float4*)(x + i + 4);
    unsigned short v[8] = {f2bf(a.x), f2bf(a.y), f2bf(a.z), f2bf(a.w),
                           f2bf(b.x), f2bf(b.y), f2bf(b.z), f2bf(b.w)};
    *(uint4*)(xb + i) = *(const uint4*)v;
    return;
  }

  // ---- transpose+cast a weight matrix: fp32 [R=1024, C] -> bf16 [C, 1024] ----
  const float* in;
  unsigned short* out;
  int C, bx, by;
  if (id < 4096 + 768) {
    const int t1 = id - 4096;
    in = w_qkv; out = wqkvT; C = QKVCOL;
    bx = t1 % 48; by = t1 / 48;
  } else {
    const int t2 = id - 4096 - 768;
    in = w_out; out = woutT; C = CDIM;
    bx = t2 & 15; by = t2 >> 4;
  }
  const int R  = CDIM;
  const int r0 = by * 64;
  const int c0 = bx * 64;
  const int tr = t >> 2;
  const int tc = (t & 3) * 16;

  const float4* src = (const float4*)(in + (size_t)(r0 + tr) * C + c0 + tc);
#pragma unroll
  for (int i = 0; i < 4; i++)
    *(float4*)&tile[tr][tc + 4 * i] = src[i];
  __syncthreads();

  unsigned short vals[16];
#pragma unroll
  for (int k = 0; k < 16; k++) vals[k] = f2bf(tile[tc + k][tr]);
  uint4* dst = (uint4*)(out + (size_t)(c0 + tr) * R + r0 + tc);
  dst[0] = ((const uint4*)vals)[0];
  dst[1] = ((const uint4*)vals)[1];
}

// ---------------------------------------------------------------------------
// QKV GEMM, R14: BK=64 swizzled staging (verified R8/R9) + T4 counted-vmcnt
// double-buffer with RAW s_barrier (not __syncthreads). Mechanism: the
// compiler emits s_waitcnt vmcnt(0) before every __syncthreads (the ~20%
// structural drain, m233/§5); R10 proved stage-early can't help under that.
// T4 (m218: counted-vs-drain +38-73%; m201 template) replaces the drain
// with vmcnt(8): the NEXT tile's 8 global_load_lds stay in flight across
// the whole compute phase; only the CURRENT tile's 8 are waited.
// Ordering: [STAGE(buf^1)] -> vmcnt(8) -> s_barrier -> sched_barrier(0)
// (pins ds_reads below barrier) -> ds_read+MFMA -> sched_barrier(0) (pins
// MFMA+lgkmcnt above, rule #18) -> s_barrier (no wave holds in-flight reads
// of buf when it is re-staged next iter). Last iter waits vmcnt(0).
// MFMA operand order unchanged -> bit-exact if race-free. LDS 64KB.
// V^T fused epilogue (R9) + Q scale 0.125*log2(e) unchanged.
// ---------------------------------------------------------------------------
__global__ __launch_bounds__(256) void gemm_qkv(
    const unsigned short* __restrict__ A, const unsigned short* __restrict__ Bt,
    unsigned short* __restrict__ Qb, unsigned short* __restrict__ Kb,
    unsigned short* __restrict__ vt) {
  __shared__ unsigned short ldsA[2][128 * 64];
  __shared__ unsigned short ldsB[2][128 * 64];

  const int tid  = threadIdx.x;
  const int lane = tid & 63;
  const int wave = tid >> 6;
  const int m0   = blockIdx.y * 128;
  const int n0   = blockIdx.x * 128;
  const int wr   = wave >> 1;
  const int wc   = wave & 1;
  const int quad = lane >> 4;
  const int l16  = lane & 15;

  f32x4 acc[4][4] = {};
  const int rsub = lane >> 3;          // 0..7   (row within 8-row chunk)
  const int csub = (lane & 7) * 8;     // 0..56  (col granule)

  // hoisted conflict-free read bases (v7 formulas, 64-elem rows)
  const int cx34 = (quad * 8) ^ ((l16 & 3) << 3);
  const int rb0  = l16 * 64 + ((l16 & 4) << 3) + cx34;          // ks=0
  const int rb1  = l16 * 64 + (32 ^ ((l16 & 4) << 3)) + cx34;   // ks=1

#define STAGE_G(buf, k0)                                                       \
  {                                                                            \
    _Pragma("unroll")                                                          \
    for (int i = 0; i < 4; i++) {                                              \
      const int rowbase = i * 32 + wave * 8;                                   \
      const int row  = rowbase + rsub;                                         \
      const int colS = csub ^ ((row & 7) * 8);                                 \
      load16_to_lds(A  + (size_t)(m0 + row) * CDIM + (k0) + colS,              \
                    &ldsA[buf][rowbase * 64]);                                 \
      load16_to_lds(Bt + (size_t)(n0 + row) * CDIM + (k0) + colS,              \
                    &ldsB[buf][rowbase * 64]);                                 \
    }                                                                          \
  }

  STAGE_G(0, 0);

  for (int t = 0; t < 16; ++t) {
    const int buf = t & 1;
    if (t + 1 < 16) {
      STAGE_G(buf ^ 1, (t + 1) * 64);
      asm volatile("s_waitcnt vmcnt(8)" ::: "memory");   // current tile done; next 8 in flight
    } else {
      asm volatile("s_waitcnt vmcnt(0)" ::: "memory");   // last tile: full drain
    }
    __builtin_amdgcn_s_barrier();          // raw barrier — no compiler drain
    __builtin_amdgcn_sched_barrier(0);     // ds_reads must stay below barrier

    bf16x8 fa[4][2], fb[4][2];
#pragma unroll
    for (int i = 0; i < 4; i++) {
      fa[i][0] = *(const bf16x8*)&ldsA[buf][wr * 4096 + i * 1024 + rb0];
      fa[i][1] = *(const bf16x8*)&ldsA[buf][wr * 4096 + i * 1024 + rb1];
    }
#pragma unroll
    for (int j = 0; j < 4; j++) {
      fb[j][0] = *(const bf16x8*)&ldsB[buf][wc * 4096 + j * 1024 + rb0];
      fb[j][1] = *(const bf16x8*)&ldsB[buf][wc * 4096 + j * 1024 + rb1];
    }

#pragma unroll
    for (int i = 0; i < 4; i++)
#pragma unroll
      for (int j = 0; j < 4; j++) {
        acc[i][j] = __builtin_amdgcn_mfma_f32_16x16x32_bf16(fa[i][0], fb[j][0], acc[i][j], 0, 0, 0);
        acc[i][j] = __builtin_amdgcn_mfma_f32_16x16x32_bf16(fa[i][1], fb[j][1], acc[i][j], 0, 0, 0);
      }

    __builtin_amdgcn_sched_barrier(0);     // MFMAs + lgkmcnt pinned above (rule #18)
    __builtin_amdgcn_s_barrier();          // all waves done reading buf
  }

  const int seg = n0 >> 10;                       // 0=Q 1=K 2=V
  if (seg == 2) {
    // V: write directly transposed into vt [b*16+h][d][t] (bit-exact values)
#pragma unroll
    for (int i = 0; i < 4; i++) {
      const int row = m0 + wr * 64 + i * 16 + quad * 4;   // = b*2048 + t0
      const int bb  = row >> 11;
      const int t0  = row & 2047;                          // t0 % 4 == 0
#pragma unroll
      for (int j = 0; j < 4; j++) {
        const int col = ((n0 & 1023) + wc * 64 + j * 16 + l16);  // h*64+d
        unsigned short v4[4];
#pragma unroll
        for (int r = 0; r < 4; r++) v4[r] = f2bf(acc[i][j][r]);
        *(uint2*)(vt + ((size_t)(bb * 16 + (col >> 6)) * 64 + (col & 63)) * TSEQ + t0)
            = *(const uint2*)v4;
      }
    }
  } else {
    unsigned short* dst = seg == 0 ? Qb : Kb;
    const float scl = seg == 0 ? 0.18033688f : 1.0f;  // 0.125*log2(e)
#pragma unroll
    for (int i = 0; i < 4; i++) {
      const int row = m0 + wr * 64 + i * 16 + quad * 4;
#pragma unroll
      for (int j = 0; j < 4; j++) {
        const int col = ((n0 & 1023) + wc * 64 + j * 16 + l16);
#pragma unroll
        for (int r = 0; r < 4; r++)
          dst[(size_t)(row + r) * CDIM + col] = f2bf(acc[i][j][r] * scl);
      }
    }
  }
}

// ---------------------------------------------------------------------------
// Out-projection GEMM, R14: same T4 counted-vmcnt double-buffer as gemm_qkv.
// ---------------------------------------------------------------------------
__global__ __launch_bounds__(256) void gemm_out(
    const unsigned short* __restrict__ A, const unsigned short* __restrict__ Bt,
    float* __restrict__ Cmat, const float* __restrict__ bias) {
  __shared__ unsigned short ldsA[2][128 * 64];
  __shared__ unsigned short ldsB[2][128 * 64];

  const int tid  = threadIdx.x;
  const int lane = tid & 63;
  const int wave = tid >> 6;
  const int m0   = blockIdx.y * 128;
  const int n0   = blockIdx.x * 128;
  const int wr   = wave >> 1;
  const int wc   = wave & 1;
  const int quad = lane >> 4;
  const int l16  = lane & 15;

  f32x4 acc[4][4] = {};
  const int rsub = lane >> 3;
  const int csub = (lane & 7) * 8;

  const int cx34 = (quad * 8) ^ ((l16 & 3) << 3);
  const int rb0  = l16 * 64 + ((l16 & 4) << 3) + cx34;
  const int rb1  = l16 * 64 + (32 ^ ((l16 & 4) << 3)) + cx34;

  STAGE_G(0, 0);

  for (int t = 0; t < 16; ++t) {
    const int buf = t & 1;
    if (t + 1 < 16) {
      STAGE_G(buf ^ 1, (t + 1) * 64);
      asm volatile("s_waitcnt vmcnt(8)" ::: "memory");
    } else {
      asm volatile("s_waitcnt vmcnt(0)" ::: "memory");
    }
    __builtin_amdgcn_s_barrier();
    __builtin_amdgcn_sched_barrier(0);

    bf16x8 fa[4][2], fb[4][2];
#pragma unroll
    for (int i = 0; i < 4; i++) {
      fa[i][0] = *(const bf16x8*)&ldsA[buf][wr * 4096 + i * 1024 + rb0];
      fa[i][1] = *(const bf16x8*)&ldsA[buf][wr * 4096 + i * 1024 + rb1];
    }
#pragma unroll
    for (int j = 0; j < 4; j++) {
      fb[j][0] = *(const bf16x8*)&ldsB[buf][wc * 4096 + j * 1024 + rb0];
      fb[j][1] = *(const bf16x8*)&ldsB[buf][wc * 4096 + j * 1024 + rb1];
    }

#pragma unroll
    for (int i = 0; i < 4; i++)
#pragma unroll
      for (int j = 0; j < 4; j++) {
        acc[i][j] = __builtin_amdgcn_mfma_f32_16x16x32_bf16(fa[i][0], fb[j][0], acc[i][j], 0, 0, 0);
        acc[i][j] = __builtin_amdgcn_mfma_f32_16x16x32_bf16(fa[i][1], fb[j][1], acc[i][j], 0, 0, 0);
      }

    __builtin_amdgcn_sched_barrier(0);
    __builtin_amdgcn_s_barrier();
  }

#pragma unroll
  for (int i = 0; i < 4; i++) {
    const int row = m0 + wr * 64 + i * 16 + quad * 4;
#pragma unroll
    for (int j = 0; j < 4; j++) {
      const int col = n0 + wc * 64 + j * 16 + l16;
      const float bv2 = bias[col];
#pragma unroll
      for (int r = 0; r < 4; r++)
        Cmat[(size_t)(row + r) * CDIM + col] = acc[i][j][r] + bv2;
    }
  }
}

// ---------------------------------------------------------------------------
// MFMA causal flash attention, v10 — VERIFIED R7/R8/R9/R11/R13 (~75-76µs,
// absmax 0.015625, 0 bank conflicts) = v7 structure + CU load-balance remap.
// UNCHANGED.
// ---------------------------------------------------------------------------
__global__ __launch_bounds__(256, 2) void flash_attn_mfma(
    const unsigned short* __restrict__ Qb, const unsigned short* __restrict__ Kb,
    const unsigned short* __restrict__ vt, unsigned short* __restrict__ aout) {
  __shared__ unsigned short K_lds[2 * 64 * 64];     // double-buffered
  __shared__ unsigned short V_lds[2 * 64 * 64];     // double-buffered
  __shared__ unsigned short P_lds[4][2][32 * 64];   // [wave][group][32 rows]

  const int tid  = threadIdx.x;
  const int lane = tid & 63;
  const int wave = tid >> 6;          // 0..3
  const int id   = blockIdx.x;
  const int bh   = id & 63;           // XCD bucket; blocks id,id+256 share bh
  const int pr   = id >> 6;           // 0..7 raw
  const int p    = pr < 4 ? pr : 11 - pr;   // balance remap: pairs sum 50/50/50/50
  const int b    = bh >> 4, h = bh & 15;
  const int quad = lane >> 4;
  const int l16  = lane & 15;

  const int j    = p * 4 + wave;      // 0..31
  const int wqA  = j * 32;
  const int wqB  = (63 - j) * 32;
  const int endA = (wqA >> 6) + 1;    // active tiles for group A
  const int endB = (wqB >> 6) + 1;
  const int KT   = ((63 - 4 * p) >> 1) + 1;   // block-uniform iterations

  // ---- hoisted swizzle bases (kt-invariant) ----
  const int cx34   = (quad * 8) ^ ((l16 & 3) << 3);          // bits 3-4
  const int rb_ks0 = l16 * 64 + ((l16 & 4) << 3) + cx34;     // ks=0
  const int rb_ks1 = l16 * 64 + (32 ^ ((l16 & 4) << 3)) + cx34;  // ks=1
  int pwoff[4][4];
#pragma unroll
  for (int r = 0; r < 4; r++)
#pragma unroll
    for (int nt = 0; nt < 4; nt++)
      pwoff[r][nt] = (quad * 4 + r) * 64
                   + ((nt * 16) ^ (((quad & 1) << 5) | ((r & 2) << 3)))
                   + (l16 ^ ((r & 1) << 3));
  // staging write side
  const int srow = tid >> 2;          // 0..63
  const int scol = (tid & 3) * 16;    // 0,16,32,48
  const int ms   = (srow & 7) << 3;
  const int st0  = srow * 64 + (scol ^ ms);
  const int st1  = srow * 64 + ((scol + 8) ^ ms);

  // Q A-frags for both groups (Q pre-scaled by 0.125*log2e)
  bf16x8 aqA[2][2], aqB[2][2];
#pragma unroll
  for (int mt = 0; mt < 2; mt++)
#pragma unroll
    for (int ks = 0; ks < 2; ks++) {
      aqA[mt][ks] = *(const bf16x8*)(Qb + (size_t)(b * TSEQ + wqA + mt * 16 + l16) * CDIM
                                        + h * 64 + ks * 32 + quad * 8);
      aqB[mt][ks] = *(const bf16x8*)(Qb + (size_t)(b * TSEQ + wqB + mt * 16 + l16) * CDIM
                                        + h * 64 + ks * 32 + quad * 8);
    }

  f32x4 OA[2][4] = {}, OB[2][4] = {};
  f32x4 lA[2] = {}, lB[2] = {};

  bf16x8 ones;
#pragma unroll
  for (int jj = 0; jj < 8; jj++) ones[jj] = (__bf16)1.0f;

  const unsigned short* Kg = Kb + (size_t)b * TSEQ * CDIM + h * 64;
  const unsigned short* Vg = vt + (size_t)bh * 64 * TSEQ;
  unsigned short* pwA = &P_lds[wave][0][0];
  unsigned short* pwB = &P_lds[wave][1][0];

  // preload tile 0 into staging registers
  uint4 kr0, kr1, vr0, vr1;
  {
    const uint4* ks_ = (const uint4*)(Kg + (size_t)srow * CDIM + scol);
    kr0 = ks_[0]; kr1 = ks_[1];
    const uint4* vs_ = (const uint4*)(Vg + (size_t)srow * TSEQ + scol);
    vr0 = vs_[0]; vr1 = vs_[1];
  }

  for (int kt = 0; kt < KT; kt++) {
    const int kbase = kt * 64;
    const int bo    = (kt & 1) << 12;    // double-buffer offset (u16 units)

    *(uint4*)&K_lds[bo + st0] = kr0;
    *(uint4*)&K_lds[bo + st1] = kr1;
    *(uint4*)&V_lds[bo + st0] = vr0;
    *(uint4*)&V_lds[bo + st1] = vr1;
    __syncthreads();   // staged tile visible; ONE barrier per iteration

    if (kt + 1 < KT) {
      const uint4* ks_ = (const uint4*)(Kg + (size_t)(kbase + 64 + srow) * CDIM + scol);
      kr0 = ks_[0]; kr1 = ks_[1];
      const uint4* vs_ = (const uint4*)(Vg + (size_t)srow * TSEQ + kbase + 64 + scol);
      vr0 = vs_[0]; vr1 = vs_[1];
    }

    const bool dA = (kt < endA);
    const bool dB = (kt < endB);

    // ---- S phase (both groups) ----
    f32x4 SA[2][4] = {}, SB[2][4] = {};
#pragma unroll
    for (int nt = 0; nt < 4; nt++)
#pragma unroll
      for (int ks = 0; ks < 2; ks++) {
        bf16x8 bk = *(const bf16x8*)&K_lds[bo + nt * 1024 + (ks ? rb_ks1 : rb_ks0)];
        if (dA) {
          SA[0][nt] = __builtin_amdgcn_mfma_f32_16x16x32_bf16(aqA[0][ks], bk, SA[0][nt], 0, 0, 0);
          SA[1][nt] = __builtin_amdgcn_mfma_f32_16x16x32_bf16(aqA[1][ks], bk, SA[1][nt], 0, 0, 0);
        }
        if (dB) {
          SB[0][nt] = __builtin_amdgcn_mfma_f32_16x16x32_bf16(aqB[0][ks], bk, SB[0][nt], 0, 0, 0);
          SB[1][nt] = __builtin_amdgcn_mfma_f32_16x16x32_bf16(aqB[1][ks], bk, SB[1][nt], 0, 0, 0);
        }
      }

    // ---- P phase (exp2; mask only on diagonal tiles) ----
    if (dA) {
      const bool maskedA = (kbase + 64 > wqA);
#pragma unroll
      for (int mt = 0; mt < 2; mt++) {
#pragma unroll
        for (int nt = 0; nt < 4; nt++)
#pragma unroll
          for (int r = 0; r < 4; r += 2) {
            float s0 = SA[mt][nt][r], s1 = SA[mt][nt][r + 1];
            if (maskedA) {
              const int qrow = wqA + mt * 16 + quad * 4 + r;
              const int key  = kbase + nt * 16 + l16;
              s0 = (key <= qrow)     ? s0 : -1e30f;
              s1 = (key <= qrow + 1) ? s1 : -1e30f;
            }
            __hip_bfloat162 p2 = __float22bfloat162_rn(make_float2(EXP2F(s0), EXP2F(s1)));
            unsigned int u; __builtin_memcpy(&u, &p2, 4);
            pwA[pwoff[r    ][nt] + mt * 1024] = (unsigned short)u;
            pwA[pwoff[r + 1][nt] + mt * 1024] = (unsigned short)(u >> 16);
          }
      }
    }
    if (dB) {
      const bool maskedB = (kbase + 64 > wqB);
#pragma unroll
      for (int mt = 0; mt < 2; mt++) {
#pragma unroll
        for (int nt = 0; nt < 4; nt++)
#pragma unroll
          for (int r = 0; r < 4; r += 2) {
            float s0 = SB[mt][nt][r], s1 = SB[mt][nt][r + 1];
            if (maskedB) {
              const int qrow = wqB + mt * 16 + quad * 4 + r;
              const int key  = kbase + nt * 16 + l16;
              s0 = (key <= qrow)     ? s0 : -1e30f;
              s1 = (key <= qrow + 1) ? s1 : -1e30f;
            }
            __hip_bfloat162 p2 = __float22bfloat162_rn(make_float2(EXP2F(s0), EXP2F(s1)));
            unsigned int u; __builtin_memcpy(&u, &p2, 4);
            pwB[pwoff[r    ][nt] + mt * 1024] = (unsigned short)u;
            pwB[pwoff[r + 1][nt] + mt * 1024] = (unsigned short)(u >> 16);
          }
      }
    }

    // ---- O phase (both groups) ----
#pragma unroll
    for (int ks = 0; ks < 2; ks++) {
      const int rb = ks ? rb_ks1 : rb_ks0;
      bf16x8 bv[4];
#pragma unroll
      for (int nt = 0; nt < 4; nt++)
        bv[nt] = *(const bf16x8*)&V_lds[bo + nt * 1024 + rb];
      if (dA) {
#pragma unroll
        for (int mt = 0; mt < 2; mt++) {
          bf16x8 ap = *(const bf16x8*)&pwA[mt * 1024 + rb];
          lA[mt] = __builtin_amdgcn_mfma_f32_16x16x32_bf16(ap, ones, lA[mt], 0, 0, 0);
#pragma unroll
          for (int nt = 0; nt < 4; nt++)
            OA[mt][nt] = __builtin_amdgcn_mfma_f32_16x16x32_bf16(ap, bv[nt], OA[mt][nt], 0, 0, 0);
        }
      }
      if (dB) {
#pragma unroll
        for (int mt = 0; mt < 2; mt++) {
          bf16x8 ap = *(const bf16x8*)&pwB[mt * 1024 + rb];
          lB[mt] = __builtin_amdgcn_mfma_f32_16x16x32_bf16(ap, ones, lB[mt], 0, 0, 0);
#pragma unroll
          for (int nt = 0; nt < 4; nt++)
            OB[mt][nt] = __builtin_amdgcn_mfma_f32_16x16x32_bf16(ap, bv[nt], OB[mt][nt], 0, 0, 0);
        }
      }
    }
  }

  // epilogue: O / l -> aout [b t][h d], both groups
#pragma unroll
  for (int mt = 0; mt < 2; mt++) {
    float invA[4], invB[4];
#pragma unroll
    for (int r = 0; r < 4; r++) { invA[r] = 1.0f / lA[mt][r]; invB[r] = 1.0f / lB[mt][r]; }
    unsigned short* oa = aout + (size_t)(b * TSEQ + wqA + mt * 16 + quad * 4) * CDIM + h * 64 + l16;
    unsigned short* ob = aout + (size_t)(b * TSEQ + wqB + mt * 16 + quad * 4) * CDIM + h * 64 + l16;
#pragma unroll
    for (int nt = 0; nt < 4; nt++)
#pragma unroll
      for (int r = 0; r < 4; r++) {
        oa[(size_t)r * CDIM + nt * 16] = f2bf(OA[mt][nt][r] * invA[r]);
        ob[(size_t)r * CDIM + nt * 16] = f2bf(OB[mt][nt][r] * invB[r]);
      }
  }
}

// ---------------------------------------------------------------------------
extern "C" void kernel_launch(void* const* d_in, const int* in_sizes, int n_in,
                              void* d_out, int out_size, void* d_ws, size_t ws_size,
                              hipStream_t stream) {
  (void)in_sizes; (void)n_in; (void)out_size;
  const float* x     = (const float*)d_in[0];  // [8192,1024] fp32
  const float* w_qkv = (const float*)d_in[1];  // [1024,3072] fp32
  const float* w_out = (const float*)d_in[2];  // [1024,1024] fp32
  const float* b_out = (const float*)d_in[3];  // [1024] fp32
  float* out = (float*)d_out;                  // [8192,1024] fp32

  // Workspace: 72 MiB. Layout (R9): Qb@0, Kb@16M, vt@32M, xb@48M,
  // aout@48M (aliases xb, dead after gemm_qkv), wqkvT@64M, woutT@70M.
  const size_t WS_NEED = 75497472;
  if (ws_size < WS_NEED) return;

  char* ws = (char*)d_ws;
  unsigned short* Qb    = (unsigned short*)(ws);
  unsigned short* Kb    = (unsigned short*)(ws + 16777216);
  unsigned short* vt    = (unsigned short*)(ws + 33554432);
  unsigned short* xb    = (unsigned short*)(ws + 50331648);
  unsigned short* aout  = (unsigned short*)(ws + 50331648);  // alias of xb
  unsigned short* wqkvT = (unsigned short*)(ws + 67108864);
  unsigned short* woutT = (unsigned short*)(ws + 73400320);

  // 1) merged prep: x->bf16 + both weight transposes (one launch)
  prep_all<<<dim3(4096 + 768 + 256), 256, 0, stream>>>(
      x, xb, w_qkv, wqkvT, w_out, woutT);

  // 2) QKV projection (Q pre-scaled 0.125*log2e); V written directly as vt
  gemm_qkv<<<dim3(QKVCOL / 128, MROWS / 128), 256, 0, stream>>>(xb, wqkvT, Qb, Kb, vt);

  // 3) balanced block-shared MFMA flash attention -> aout (overwrites xb)
  flash_attn_mfma<<<dim3(8 * 64), 256, 0, stream>>>(Qb, Kb, vt, aout);

  // 4) out-projection + bias
  gemm_out<<<dim3(CDIM / 128, MROWS / 128), 256, 0, stream>>>(aout, woutT, out, b_out);
}